// Round 2
// baseline (1538.702 us; speedup 1.0000x reference)
//
#include <hip/hip_runtime.h>
#include <cstdint>

// ---------------- problem constants ----------------
#define SEQ   386
#define NP1   385
#define HDIM  256
#define G4    1024
#define EMBD  128
#define LABV  128
#define OUTC  129   // 128 label + 1 split

typedef _Float16 h2 __attribute__((ext_vector_type(2)));
typedef _Float16 f16x8 __attribute__((ext_vector_type(8)));
typedef float    f32x4 __attribute__((ext_vector_type(4)));

__device__ __forceinline__ uint32_t pack2(float a, float b) {
    h2 v; v[0] = (_Float16)a; v[1] = (_Float16)b;
    return __builtin_bit_cast(uint32_t, v);
}

__device__ __forceinline__ float dot2(uint32_t wa, uint32_t hb, float c) {
    h2 a = __builtin_bit_cast(h2, wa);
    h2 b = __builtin_bit_cast(h2, hb);
#if __has_builtin(__builtin_amdgcn_fdot2)
    return __builtin_amdgcn_fdot2(a, b, c, false);
#else
    return fmaf((float)a[1], (float)b[1], fmaf((float)a[0], (float)b[0], c));
#endif
}

__device__ __forceinline__ float sigm(float x) { return 1.f / (1.f + __expf(-x)); }
__device__ __forceinline__ float ftanh(float x) {
    x = fminf(fmaxf(x, -15.f), 15.f);
    float e = __expf(2.f * x);
    return (e - 1.f) / (e + 1.f);
}

// ---------------- workspace layout (bytes) ----------------
#define OFF_EMB   0u                       // 386*128*4      = 197632
#define OFF_GX    197632u                  // 2*386*1024*4   = 3162112
#define OFF_WREG  3359744u                 // 2*24576*16     = 786432
#define OFF_WLDS  4146176u                 // 2*1024*32*4    = 262144
#define OFF_F     4408320u                 // 385*256*4      = 394240
#define OFF_B     4802560u                 // 385*256*4      = 394240
#define OFF_DL    5196800u                 // 385*256*4      = 394240
#define OFF_DS    5591040u                 // 385*256*4      = 394240
#define OFF_W2F   5985280u                 // 32*128*8*2     = 65536 (f16 B-fragments)
// total ~6.05 MB

// ---------------- K1: embedding gather ----------------
__global__ void k_embed(const int* __restrict__ tag_ids, const int* __restrict__ word_ids,
                        const float* __restrict__ tag_emb, const float* __restrict__ word_emb,
                        float* __restrict__ emb) {
    int t = blockIdx.x, d = threadIdx.x;
    emb[t * EMBD + d] = tag_emb[tag_ids[t] * EMBD + d] + word_emb[word_ids[t] * EMBD + d];
}

// ---------------- K2: Gx[dir][t][1024] = Wx @ emb[t] + b ----------------
__global__ __launch_bounds__(256) void k_gx(const float* __restrict__ emb,
                                            const float* __restrict__ wxf, const float* __restrict__ bf_,
                                            const float* __restrict__ wxb, const float* __restrict__ bb_,
                                            float* __restrict__ gx) {
    const int dir = blockIdx.y;
    const int t0  = blockIdx.x * 8;
    const float* Wx   = dir ? wxb : wxf;
    const float* bias = dir ? bb_ : bf_;
    __shared__ float se[8 * EMBD];
    for (int idx = threadIdx.x; idx < 8 * EMBD; idx += 256) {
        int tt = t0 + (idx >> 7);
        se[idx] = (tt < SEQ) ? emb[tt * EMBD + (idx & 127)] : 0.f;
    }
    __syncthreads();
    const float4* se4 = (const float4*)se;
    for (int q = 0; q < 4; ++q) {
        int r = threadIdx.x + q * 256;
        float bv = bias[r];
        float acc[8];
#pragma unroll
        for (int tt = 0; tt < 8; ++tt) acc[tt] = bv;
        const float4* wrow = (const float4*)(Wx + r * EMBD);
        for (int d4 = 0; d4 < 32; ++d4) {
            float4 w = wrow[d4];
#pragma unroll
            for (int tt = 0; tt < 8; ++tt) {
                float4 e = se4[tt * 32 + d4];
                acc[tt] += w.x * e.x + w.y * e.y + w.z * e.z + w.w * e.w;
            }
        }
        for (int tt = 0; tt < 8; ++tt) {
            int t = t0 + tt;
            if (t < SEQ) gx[(dir * SEQ + t) * G4 + r] = acc[tt];
        }
    }
}

// ---------------- K3: convert Wh fp32 -> f16 packed layouts ----------------
// wreg[dir][ (q*24+g)*256 + tid ] = f16 pairs of Wh[row = tid + 256q][cols g*8 .. g*8+7]
// wlds[dir][ r*32 + c ]           = f16 pair  of Wh[r][cols 192+2c, 193+2c]
__global__ void k_wconv(const float* __restrict__ whf, const float* __restrict__ whb,
                        uint4* __restrict__ wreg, uint32_t* __restrict__ wlds) {
    const int dir = blockIdx.x;
    const float* Wh = dir ? whb : whf;
    const int y = blockIdx.y, tid = threadIdx.x;
    if (y < 96) {
        int idx = y * 256 + tid;          // [0, 24576)
        int tidd = idx & 255;
        int qg = idx >> 8;                // 0..95
        int q = qg / 24, g = qg % 24;
        int r = tidd + 256 * q;
        const float* src = Wh + r * HDIM + g * 8;
        uint4 o;
        o.x = pack2(src[0], src[1]); o.y = pack2(src[2], src[3]);
        o.z = pack2(src[4], src[5]); o.w = pack2(src[6], src[7]);
        wreg[dir * 24576 + idx] = o;
    } else {
        int idx = (y - 96) * 256 + tid;   // [0, 32768)
        int r = idx >> 5, c = idx & 31;
        wlds[dir * 32768 + r * 32 + c] = pack2(Wh[r * HDIM + 192 + 2 * c], Wh[r * HDIM + 193 + 2 * c]);
    }
}

// ---------------- K4: the two LSTMs (1 block per direction, 256 threads) ----------------
// v3 geometry: 256 threads = 4 waves = 1 wave/SIMD at waves_per_eu(1,1) -> 512-VGPR
// budget per wave. Thread tid owns gate rows {tid, tid+256, tid+512, tid+768} =
// {i,f,g,o} of element tid: all four gates finish IN-THREAD, so there is no gate
// LDS round-trip, the activation runs in-thread, and only the 2-byte h goes to LDS
// (double-buffered by step parity -> ONE barrier per step). Weight cols 0..191 live
// in 96 uint4 = 384 arch VGPRs (+ ~45 misc < 450 no-spill cliff); cols 192..255
// stream from LDS (stride-36 swizzle, phase-conflict-free for b128).
__global__ __launch_bounds__(256, 1)
__attribute__((amdgpu_waves_per_eu(1, 1)))
void k_lstm(const uint4* __restrict__ wreg,
            const uint32_t* __restrict__ wlds,
            const float* __restrict__ gx,
            float* __restrict__ fout, float* __restrict__ bout) {
    const int dir = blockIdx.x;
    const int tid = threadIdx.x;                  // 0..255
    __shared__ uint32_t wl[1024 * 36];            // 147456 B
    __shared__ uint32_t hbuf[2][160];             // f16 h pairs, double-buffered

    // stage wlds -> wl with stride-36 swizzle (16B-aligned: 144*r + 16*c)
    const uint4* wsrc4 = (const uint4*)(wlds + dir * 32768);
    for (int i4 = tid; i4 < 8192; i4 += 256) {
        uint4 v = wsrc4[i4];
        *(uint4*)&wl[(i4 >> 3) * 36 + (i4 & 7) * 4] = v;
    }
    if (tid < 160) { hbuf[0][tid] = 0u; hbuf[1][tid] = 0u; }

    // weight registers: w[q][g] = rows tid+256q, cols 8g..8g+7
    uint4 w[4][24];
    const uint4* wr = wreg + dir * 24576;
#pragma unroll
    for (int q = 0; q < 4; ++q)
#pragma unroll
        for (int g = 0; g < 24; ++g)
            w[q][g] = wr[(q * 24 + g) * 256 + tid];

    const float* gxd = gx + dir * SEQ * G4;
    float c = 0.f;
    const int tfirst = dir ? (SEQ - 1) : 0;
    float gxv[4], gn[4];
#pragma unroll
    for (int q = 0; q < 4; ++q) gxv[q] = gxd[tfirst * G4 + q * 256 + tid];

    const uint4* wlq0 = (const uint4*)(wl + (tid)       * 36);
    const uint4* wlq1 = (const uint4*)(wl + (tid + 256) * 36);
    const uint4* wlq2 = (const uint4*)(wl + (tid + 512) * 36);
    const uint4* wlq3 = (const uint4*)(wl + (tid + 768) * 36);
    __syncthreads();

    for (int s = 0; s < SEQ; ++s) {
        const int t = dir ? (SEQ - 1 - s) : s;
        if (s < SEQ - 1) {
            int tn = dir ? (SEQ - 2 - s) : (s + 1);
#pragma unroll
            for (int q = 0; q < 4; ++q) gn[q] = gxd[tn * G4 + q * 256 + tid];
        } else {
#pragma unroll
            for (int q = 0; q < 4; ++q) gn[q] = 0.f;
        }
        float a0 = gxv[0], a1 = gxv[1], a2 = gxv[2], a3 = gxv[3];
        const uint4* hb = (const uint4*)hbuf[s & 1];

        // register-resident cols 0..191 (h pairs 0..95)
#pragma unroll
        for (int g = 0; g < 24; ++g) {
            uint4 hv = hb[g];
            a0 = dot2(w[0][g].x, hv.x, a0); a0 = dot2(w[0][g].y, hv.y, a0);
            a0 = dot2(w[0][g].z, hv.z, a0); a0 = dot2(w[0][g].w, hv.w, a0);
            a1 = dot2(w[1][g].x, hv.x, a1); a1 = dot2(w[1][g].y, hv.y, a1);
            a1 = dot2(w[1][g].z, hv.z, a1); a1 = dot2(w[1][g].w, hv.w, a1);
            a2 = dot2(w[2][g].x, hv.x, a2); a2 = dot2(w[2][g].y, hv.y, a2);
            a2 = dot2(w[2][g].z, hv.z, a2); a2 = dot2(w[2][g].w, hv.w, a2);
            a3 = dot2(w[3][g].x, hv.x, a3); a3 = dot2(w[3][g].y, hv.y, a3);
            a3 = dot2(w[3][g].z, hv.z, a3); a3 = dot2(w[3][g].w, hv.w, a3);
        }
        // LDS-resident cols 192..255 (h pairs 96..127)
#pragma unroll
        for (int g = 0; g < 8; ++g) {
            uint4 hv = hb[24 + g];
            uint4 v0 = wlq0[g];
            uint4 v1 = wlq1[g];
            uint4 v2 = wlq2[g];
            uint4 v3 = wlq3[g];
            a0 = dot2(v0.x, hv.x, a0); a0 = dot2(v0.y, hv.y, a0);
            a0 = dot2(v0.z, hv.z, a0); a0 = dot2(v0.w, hv.w, a0);
            a1 = dot2(v1.x, hv.x, a1); a1 = dot2(v1.y, hv.y, a1);
            a1 = dot2(v1.z, hv.z, a1); a1 = dot2(v1.w, hv.w, a1);
            a2 = dot2(v2.x, hv.x, a2); a2 = dot2(v2.y, hv.y, a2);
            a2 = dot2(v2.z, hv.z, a2); a2 = dot2(v2.w, hv.w, a2);
            a3 = dot2(v3.x, hv.x, a3); a3 = dot2(v3.y, hv.y, a3);
            a3 = dot2(v3.z, hv.z, a3); a3 = dot2(v3.w, hv.w, a3);
        }

        // in-thread activation: a0=i, a1=f, a2=g, a3=o for element tid
        c = sigm(a1) * c + sigm(a0) * ftanh(a2);
        float h = sigm(a3) * ftanh(c);
        ((_Float16*)hbuf[(s + 1) & 1])[tid] = (_Float16)h;
        if (!dir) { if (t < NP1) fout[t * HDIM + tid] = h; }
        else      { if (t >= 1)  bout[(t - 1) * HDIM + tid] = h; }
        __syncthreads();
        gxv[0] = gn[0]; gxv[1] = gn[1]; gxv[2] = gn[2]; gxv[3] = gn[3];
    }
}

// ---------------- K5: D matrices ----------------
__global__ __launch_bounds__(256) void k_dmat(const float* __restrict__ fm, const float* __restrict__ bm,
                                              const float* __restrict__ lw1, const float* __restrict__ sw1,
                                              float* __restrict__ dlab, float* __restrict__ dspl) {
    const int t0 = blockIdx.x * 8;
    const int tid = threadIdx.x;
    __shared__ float fs[8 * HDIM], bs[8 * HDIM];
    for (int idx = tid; idx < 8 * HDIM; idx += 256) {
        int tt = t0 + (idx >> 8);
        float fv = 0.f, bv = 0.f;
        if (tt < NP1) { fv = fm[tt * HDIM + (idx & 255)]; bv = bm[tt * HDIM + (idx & 255)]; }
        fs[idx] = fv; bs[idx] = bv;
    }
    __syncthreads();
    float al[8], asp[8];
#pragma unroll
    for (int q = 0; q < 8; ++q) { al[q] = 0.f; asp[q] = 0.f; }
    const float4* lrow = (const float4*)(lw1 + tid * 512);
    const float4* srow = (const float4*)(sw1 + tid * 512);
    const float4* fs4 = (const float4*)fs;
    const float4* bs4 = (const float4*)bs;
    for (int d4 = 0; d4 < 64; ++d4) {
        float4 wlv = lrow[d4], wsv = srow[d4];
#pragma unroll
        for (int tt = 0; tt < 8; ++tt) {
            float4 e = fs4[tt * 64 + d4];
            al[tt]  += wlv.x * e.x + wlv.y * e.y + wlv.z * e.z + wlv.w * e.w;
            asp[tt] += wsv.x * e.x + wsv.y * e.y + wsv.z * e.z + wsv.w * e.w;
        }
    }
    for (int d4 = 0; d4 < 64; ++d4) {
        float4 wlv = lrow[64 + d4], wsv = srow[64 + d4];
#pragma unroll
        for (int tt = 0; tt < 8; ++tt) {
            float4 e = bs4[tt * 64 + d4];
            al[tt]  -= wlv.x * e.x + wlv.y * e.y + wlv.z * e.z + wlv.w * e.w;
            asp[tt] -= wsv.x * e.x + wsv.y * e.y + wsv.z * e.z + wsv.w * e.w;
        }
    }
    for (int tt = 0; tt < 8; ++tt) {
        int t = t0 + tt;
        if (t < NP1) { dlab[t * HDIM + tid] = al[tt]; dspl[t * HDIM + tid] = asp[tt]; }
    }
}

// ---------------- K6: pack lab_w2 into f16 MFMA B-fragments ----------------
// w2f[kb8][m][j] = (f16) lw2[m][kb8*8+j],  kb8=k>>3, j=k&7
__global__ void k_w2f(const float* __restrict__ lw2, _Float16* __restrict__ w2f) {
    int m = blockIdx.x, k = threadIdx.x;
    w2f[(((k >> 3) * LABV) + m) * 8 + (k & 7)] = (_Float16)lw2[m * HDIM + k];
}

// ---------------- K7: fused output kernel (MFMA f16) ----------------
// block = (jt, i); 256 threads (4 waves); out[i, jt*32 .. +31, 0..128]
// wave w owns m-tiles {2w, 2w+1}; both 16-row j-tiles; K=256 in 8 mfma steps.
__global__ __launch_bounds__(256) void k_out(const float* __restrict__ dlab, const float* __restrict__ dspl,
                                             const float* __restrict__ lb1, const float* __restrict__ sb1,
                                             const _Float16* __restrict__ w2f, const float* __restrict__ lb2,
                                             const float* __restrict__ sw2, const float* __restrict__ sb2,
                                             float* __restrict__ outp) {
    const int i = blockIdx.y, jtblk = blockIdx.x, tid = threadIdx.x;
    __shared__ float dli[HDIM], dsi[HDIM];
    __shared__ _Float16 hl[32 * 264];   // row stride 264 f16 (=33*16B) to spread banks

    dli[tid] = dlab[i * HDIM + tid] - lb1[tid];
    dsi[tid] = dspl[i * HDIM + tid] - sb1[tid];
    __syncthreads();

    // phase 1: hidden activations (f16) for the label MLP
    for (int j = 0; j < 32; ++j) {
        int jj = jtblk * 32 + j;
        float v = 0.f;
        if (jj < NP1) v = fmaxf(dlab[jj * HDIM + tid] - dli[tid], 0.f);
        hl[j * 264 + tid] = (_Float16)v;
    }

    // phase 1.5: split scores
    {
        int w = tid >> 6, l = tid & 63;
        float sw2v[4];
#pragma unroll
        for (int cc = 0; cc < 4; ++cc) sw2v[cc] = sw2[l + 64 * cc];
        float sb2v = sb2[0];
        for (int q = 0; q < 8; ++q) {
            int jj = jtblk * 32 + w * 8 + q;
            if (jj < NP1) {
                float sum = 0.f;
#pragma unroll
                for (int cc = 0; cc < 4; ++cc) {
                    int k = l + 64 * cc;
                    float v = fmaxf(dspl[jj * HDIM + k] - dsi[k], 0.f);
                    sum += v * sw2v[cc];
                }
#pragma unroll
                for (int off = 32; off > 0; off >>= 1) sum += __shfl_down(sum, off, 64);
                if (l == 0) outp[(size_t)(i * NP1 + jj) * OUTC + 128] = sum + sb2v;
            }
        }
    }
    __syncthreads();

    // phase 2: label GEMM via mfma_f32_16x16x32_f16
    const int w = tid >> 6, l = tid & 63;
    const int q = l >> 4, c16 = l & 15;
    f32x4 acc[2][2];
#pragma unroll
    for (int a = 0; a < 2; ++a)
#pragma unroll
        for (int b = 0; b < 2; ++b) acc[a][b] = (f32x4){0.f, 0.f, 0.f, 0.f};

    const int mt0 = w * 2;
#pragma unroll
    for (int kb = 0; kb < 8; ++kb) {
        // A-frags: lane holds hl[jt*16 + c16][kb*32 + q*8 .. +7]
        f16x8 a0 = *(const f16x8*)(hl + (0 * 16 + c16) * 264 + kb * 32 + q * 8);
        f16x8 a1 = *(const f16x8*)(hl + (1 * 16 + c16) * 264 + kb * 32 + q * 8);
        // B-frags: lane holds w2f[kb*4+q][mt*16 + c16][0..7]
        f16x8 b0 = *(const f16x8*)(w2f + (((kb * 4 + q) * LABV) + mt0 * 16 + c16) * 8);
        f16x8 b1 = *(const f16x8*)(w2f + (((kb * 4 + q) * LABV) + (mt0 + 1) * 16 + c16) * 8);
        acc[0][0] = __builtin_amdgcn_mfma_f32_16x16x32_f16(a0, b0, acc[0][0], 0, 0, 0);
        acc[0][1] = __builtin_amdgcn_mfma_f32_16x16x32_f16(a0, b1, acc[0][1], 0, 0, 0);
        acc[1][0] = __builtin_amdgcn_mfma_f32_16x16x32_f16(a1, b0, acc[1][0], 0, 0, 0);
        acc[1][1] = __builtin_amdgcn_mfma_f32_16x16x32_f16(a1, b1, acc[1][1], 0, 0, 0);
    }

    // epilogue: C/D layout col = lane&15, row = q*4 + reg
#pragma unroll
    for (int mb = 0; mb < 2; ++mb) {
        int m = (mt0 + mb) * 16 + c16;
        float bias = lb2[m];
#pragma unroll
        for (int jt = 0; jt < 2; ++jt) {
#pragma unroll
            for (int r = 0; r < 4; ++r) {
                int jj = jtblk * 32 + jt * 16 + q * 4 + r;
                if (jj < NP1) outp[(size_t)(i * NP1 + jj) * OUTC + m] = acc[jt][mb][r] + bias;
            }
        }
    }
}

// ---------------- launcher ----------------
extern "C" void kernel_launch(void* const* d_in, const int* in_sizes, int n_in,
                              void* d_out, int out_size, void* d_ws, size_t ws_size,
                              hipStream_t stream) {
    const int*   tag_ids  = (const int*)d_in[0];
    const int*   word_ids = (const int*)d_in[1];
    const float* tag_emb  = (const float*)d_in[2];
    const float* word_emb = (const float*)d_in[3];
    const float* wxf = (const float*)d_in[4];
    const float* whf = (const float*)d_in[5];
    const float* bf_ = (const float*)d_in[6];
    const float* wxb = (const float*)d_in[7];
    const float* whb = (const float*)d_in[8];
    const float* bb_ = (const float*)d_in[9];
    const float* lw1 = (const float*)d_in[10];
    const float* lb1 = (const float*)d_in[11];
    const float* lw2 = (const float*)d_in[12];
    const float* lb2 = (const float*)d_in[13];
    const float* sw1 = (const float*)d_in[14];
    const float* sb1 = (const float*)d_in[15];
    const float* sw2 = (const float*)d_in[16];
    const float* sb2 = (const float*)d_in[17];

    char* ws = (char*)d_ws;
    float*     emb  = (float*)(ws + OFF_EMB);
    float*     gx   = (float*)(ws + OFF_GX);
    uint4*     wreg = (uint4*)(ws + OFF_WREG);
    uint32_t*  wlds = (uint32_t*)(ws + OFF_WLDS);
    float*     fm   = (float*)(ws + OFF_F);
    float*     bm   = (float*)(ws + OFF_B);
    float*     dlab = (float*)(ws + OFF_DL);
    float*     dspl = (float*)(ws + OFF_DS);
    _Float16*  w2f  = (_Float16*)(ws + OFF_W2F);
    float*     outp = (float*)d_out;

    k_embed<<<dim3(SEQ), dim3(EMBD), 0, stream>>>(tag_ids, word_ids, tag_emb, word_emb, emb);
    k_gx   <<<dim3(49, 2), dim3(256), 0, stream>>>(emb, wxf, bf_, wxb, bb_, gx);
    k_wconv<<<dim3(2, 224), dim3(256), 0, stream>>>(whf, whb, wreg, wlds);
    k_w2f  <<<dim3(LABV), dim3(HDIM), 0, stream>>>(lw2, w2f);
    k_lstm <<<dim3(2), dim3(256), 0, stream>>>(wreg, wlds, gx, fm, bm);
    k_dmat <<<dim3(49), dim3(256), 0, stream>>>(fm, bm, lw1, sw1, dlab, dspl);
    k_out  <<<dim3(13, NP1), dim3(256), 0, stream>>>(dlab, dspl, lb1, sb1, w2f, lb2, sw2, sb2, outp);
}

// Round 3
// 1183.687 us; speedup vs baseline: 1.2999x; 1.2999x over previous
//
#include <hip/hip_runtime.h>
#include <cstdint>

// ---------------- problem constants ----------------
#define SEQ   386
#define NP1   385
#define HDIM  256
#define G4    1024
#define EMBD  128
#define LABV  128
#define OUTC  129   // 128 label + 1 split

typedef _Float16 h2 __attribute__((ext_vector_type(2)));
typedef _Float16 f16x8 __attribute__((ext_vector_type(8)));
typedef float    f32x4 __attribute__((ext_vector_type(4)));

__device__ __forceinline__ uint32_t pack2(float a, float b) {
    h2 v; v[0] = (_Float16)a; v[1] = (_Float16)b;
    return __builtin_bit_cast(uint32_t, v);
}

__device__ __forceinline__ float sigm(float x) { return 1.f / (1.f + __expf(-x)); }
__device__ __forceinline__ float ftanh(float x) {
    x = fminf(fmaxf(x, -15.f), 15.f);
    float e = __expf(2.f * x);
    return (e - 1.f) / (e + 1.f);
}

// ---------------- workspace layout (bytes) ----------------
#define OFF_EMB   0u                       // 386*128*4      = 197632
#define OFF_GX    197632u                  // 2*386*1024*4   = 3162112
#define OFF_WREG  3359744u                 // 2*384*64*16    = 786432 (MFMA A-frags kb0..5)
#define OFF_WLDS  4146176u                 // 2*128*64*16    = 262144 (MFMA A-frags kb6..7)
#define OFF_F     4408320u                 // 385*256*4      = 394240
#define OFF_B     4802560u                 // 385*256*4      = 394240
#define OFF_DL    5196800u                 // 385*256*4      = 394240
#define OFF_DS    5591040u                 // 385*256*4      = 394240
#define OFF_W2F   5985280u                 // 32*128*8*2     = 65536 (f16 B-fragments)
// total ~6.05 MB

// ---------------- K1: embedding gather ----------------
__global__ void k_embed(const int* __restrict__ tag_ids, const int* __restrict__ word_ids,
                        const float* __restrict__ tag_emb, const float* __restrict__ word_emb,
                        float* __restrict__ emb) {
    int t = blockIdx.x, d = threadIdx.x;
    emb[t * EMBD + d] = tag_emb[tag_ids[t] * EMBD + d] + word_emb[word_ids[t] * EMBD + d];
}

// ---------------- K2: Gx[dir][t][1024] = Wx @ emb[t] + b ----------------
__global__ __launch_bounds__(256) void k_gx(const float* __restrict__ emb,
                                            const float* __restrict__ wxf, const float* __restrict__ bf_,
                                            const float* __restrict__ wxb, const float* __restrict__ bb_,
                                            float* __restrict__ gx) {
    const int dir = blockIdx.y;
    const int t0  = blockIdx.x * 8;
    const float* Wx   = dir ? wxb : wxf;
    const float* bias = dir ? bb_ : bf_;
    __shared__ float se[8 * EMBD];
    for (int idx = threadIdx.x; idx < 8 * EMBD; idx += 256) {
        int tt = t0 + (idx >> 7);
        se[idx] = (tt < SEQ) ? emb[tt * EMBD + (idx & 127)] : 0.f;
    }
    __syncthreads();
    const float4* se4 = (const float4*)se;
    for (int q = 0; q < 4; ++q) {
        int r = threadIdx.x + q * 256;
        float bv = bias[r];
        float acc[8];
#pragma unroll
        for (int tt = 0; tt < 8; ++tt) acc[tt] = bv;
        const float4* wrow = (const float4*)(Wx + r * EMBD);
        for (int d4 = 0; d4 < 32; ++d4) {
            float4 w = wrow[d4];
#pragma unroll
            for (int tt = 0; tt < 8; ++tt) {
                float4 e = se4[tt * 32 + d4];
                acc[tt] += w.x * e.x + w.y * e.y + w.z * e.z + w.w * e.w;
            }
        }
        for (int tt = 0; tt < 8; ++tt) {
            int t = t0 + tt;
            if (t < SEQ) gx[(dir * SEQ + t) * G4 + r] = acc[tt];
        }
    }
}

// ---------------- K3: convert Wh fp32 -> f16 MFMA A-fragments ----------------
// Fragment (Tg, kb): lane l holds Wh[row = Tg*16 + (l&15)][col = kb*32 + (l>>4)*8 .. +7]
// as 8 f16 in a uint4 (matches mfma_f32_16x16x32_f16 A layout, same as k_out's A).
// kb 0..5 -> wreg[dir][(Tg*6+kb)*64 + lane]  (register-resident in k_lstm)
// kb 6..7 -> wldsg[dir][(kb-6)*4096 + Tg*64 + lane]  (LDS-streamed in k_lstm)
__global__ void k_wconv(const float* __restrict__ whf, const float* __restrict__ whb,
                        uint4* __restrict__ wreg, uint4* __restrict__ wldsg) {
    const int dir = blockIdx.x;
    const float* Wh = dir ? whb : whf;
    int idx = blockIdx.y * 256 + threadIdx.x;   // [0, 32768)
    int lane = idx & 63;
    int fragid = idx >> 6;                      // 0..511
    int Tg = fragid >> 3, kb = fragid & 7;
    int r  = Tg * 16 + (lane & 15);
    int c0 = kb * 32 + (lane >> 4) * 8;
    const float* src = Wh + r * HDIM + c0;
    uint4 o;
    o.x = pack2(src[0], src[1]); o.y = pack2(src[2], src[3]);
    o.z = pack2(src[4], src[5]); o.w = pack2(src[6], src[7]);
    if (kb < 6) wreg [dir * 24576 + (Tg * 6 + kb) * 64 + lane] = o;
    else        wldsg[dir * 8192 + (kb - 6) * 4096 + Tg * 64 + lane] = o;
}

// ---------------- K4: the two LSTMs via MFMA (1 block/dir, 512 threads = 8 waves) ----------------
// Wh@h as mfma_f32_16x16x32_f16 with h replicated across the 16 B-columns.
// Weights kb0..5 live in 192 regs/lane (AGPR-class is FINE here: MFMA reads AGPR
// operands natively, no copy — unlike the failed dot2 variants). kb6..7 stream
// from LDS. Wave owns 8 row-tiles, processed as 2 halves of 4 (C = 16 regs).
// Gates -> gbuf via lanes c16==tile (D cols are replicated copies); barrier;
// 256 threads do the activation in-thread; h (f16, dbuf) is the only state.
__global__ __launch_bounds__(512)
void k_lstm(const uint4* __restrict__ wreg,
            const uint4* __restrict__ wldsg,
            const float* __restrict__ gx,
            float* __restrict__ fout, float* __restrict__ bout) {
    const int dir  = blockIdx.x;
    const int tid  = threadIdx.x;             // 0..511
    const int wave = tid >> 6;
    const int lane = tid & 63;
    const int q    = lane >> 4;               // 0..3
    const int c16  = lane & 15;

    __shared__ uint4    plane[8192];          // 131072 B: [kb2][Tg64][lane64]
    __shared__ float    gbuf[1024];           // 4096 B
    __shared__ _Float16 hbuf[2][256];         // 1024 B

    // stage the two LDS weight planes (kb 6,7)
    const uint4* wg = wldsg + dir * 8192;
    for (int i = tid; i < 8192; i += 512) plane[i] = wg[i];
    if (tid < 256) hbuf[0][tid] = (_Float16)0.f;

    // register/AGPR-resident A-fragments: w[half][tile][kb], kb 0..5
    uint4 w[2][4][6];
    const uint4* wr = wreg + dir * 24576;
#pragma unroll
    for (int hh = 0; hh < 2; ++hh)
#pragma unroll
        for (int t = 0; t < 4; ++t)
#pragma unroll
            for (int kb = 0; kb < 6; ++kb)
                w[hh][t][kb] = wr[((wave * 8 + hh * 4 + t) * 6 + kb) * 64 + lane];

    const float* gxd = gx + dir * SEQ * G4;
    float c = 0.f;
    float gxv[4], gn[4];
    const int tfirst = dir ? (SEQ - 1) : 0;
    if (tid < 256) {
#pragma unroll
        for (int g = 0; g < 4; ++g) gxv[g] = gxd[tfirst * G4 + g * 256 + tid];
    }
    __syncthreads();

    for (int s = 0; s < SEQ; ++s) {
        const int t = dir ? (SEQ - 1 - s) : s;
        // prefetch next step's gx early (hidden under the MFMA phase)
        if (tid < 256) {
            if (s < SEQ - 1) {
                int tn = dir ? (SEQ - 2 - s) : (s + 1);
#pragma unroll
                for (int g = 0; g < 4; ++g) gn[g] = gxd[tn * G4 + g * 256 + tid];
            } else {
#pragma unroll
                for (int g = 0; g < 4; ++g) gn[g] = 0.f;
            }
        }

        const _Float16* hc = hbuf[s & 1];
#pragma unroll
        for (int hh = 0; hh < 2; ++hh) {
            f32x4 C0 = {0.f, 0.f, 0.f, 0.f};
            f32x4 C1 = {0.f, 0.f, 0.f, 0.f};
            f32x4 C2 = {0.f, 0.f, 0.f, 0.f};
            f32x4 C3 = {0.f, 0.f, 0.f, 0.f};
#pragma unroll
            for (int kb = 0; kb < 6; ++kb) {
                f16x8 B = *(const f16x8*)(hc + kb * 32 + q * 8);
                C0 = __builtin_amdgcn_mfma_f32_16x16x32_f16(__builtin_bit_cast(f16x8, w[hh][0][kb]), B, C0, 0, 0, 0);
                C1 = __builtin_amdgcn_mfma_f32_16x16x32_f16(__builtin_bit_cast(f16x8, w[hh][1][kb]), B, C1, 0, 0, 0);
                C2 = __builtin_amdgcn_mfma_f32_16x16x32_f16(__builtin_bit_cast(f16x8, w[hh][2][kb]), B, C2, 0, 0, 0);
                C3 = __builtin_amdgcn_mfma_f32_16x16x32_f16(__builtin_bit_cast(f16x8, w[hh][3][kb]), B, C3, 0, 0, 0);
            }
#pragma unroll
            for (int kb = 6; kb < 8; ++kb) {
                f16x8 B = *(const f16x8*)(hc + kb * 32 + q * 8);
                const uint4* pl = plane + (kb - 6) * 4096 + (wave * 8 + hh * 4) * 64 + lane;
                uint4 A0 = pl[0], A1 = pl[64], A2 = pl[128], A3 = pl[192];
                C0 = __builtin_amdgcn_mfma_f32_16x16x32_f16(__builtin_bit_cast(f16x8, A0), B, C0, 0, 0, 0);
                C1 = __builtin_amdgcn_mfma_f32_16x16x32_f16(__builtin_bit_cast(f16x8, A1), B, C1, 0, 0, 0);
                C2 = __builtin_amdgcn_mfma_f32_16x16x32_f16(__builtin_bit_cast(f16x8, A2), B, C2, 0, 0, 0);
                C3 = __builtin_amdgcn_mfma_f32_16x16x32_f16(__builtin_bit_cast(f16x8, A3), B, C3, 0, 0, 0);
            }
            // D cols are 16 identical copies; lanes c16==tile write rows q*4..q*4+3
            const int Tg0 = wave * 8 + hh * 4;
            if (c16 == 0) *(f32x4*)&gbuf[(Tg0 + 0) * 16 + q * 4] = C0;
            if (c16 == 1) *(f32x4*)&gbuf[(Tg0 + 1) * 16 + q * 4] = C1;
            if (c16 == 2) *(f32x4*)&gbuf[(Tg0 + 2) * 16 + q * 4] = C2;
            if (c16 == 3) *(f32x4*)&gbuf[(Tg0 + 3) * 16 + q * 4] = C3;
        }
        __syncthreads();

        if (tid < 256) {
            float gi = gxv[0] + gbuf[tid];
            float gf = gxv[1] + gbuf[tid + 256];
            float gg = gxv[2] + gbuf[tid + 512];
            float go = gxv[3] + gbuf[tid + 768];
            c = sigm(gf) * c + sigm(gi) * ftanh(gg);
            float h = sigm(go) * ftanh(c);
            hbuf[(s + 1) & 1][tid] = (_Float16)h;
            if (!dir) { if (t < NP1) fout[t * HDIM + tid] = h; }
            else      { if (t >= 1)  bout[(t - 1) * HDIM + tid] = h; }
        }
        __syncthreads();
#pragma unroll
        for (int g = 0; g < 4; ++g) gxv[g] = gn[g];
    }
}

// ---------------- K5: D matrices ----------------
__global__ __launch_bounds__(256) void k_dmat(const float* __restrict__ fm, const float* __restrict__ bm,
                                              const float* __restrict__ lw1, const float* __restrict__ sw1,
                                              float* __restrict__ dlab, float* __restrict__ dspl) {
    const int t0 = blockIdx.x * 8;
    const int tid = threadIdx.x;
    __shared__ float fs[8 * HDIM], bs[8 * HDIM];
    for (int idx = tid; idx < 8 * HDIM; idx += 256) {
        int tt = t0 + (idx >> 8);
        float fv = 0.f, bv = 0.f;
        if (tt < NP1) { fv = fm[tt * HDIM + (idx & 255)]; bv = bm[tt * HDIM + (idx & 255)]; }
        fs[idx] = fv; bs[idx] = bv;
    }
    __syncthreads();
    float al[8], asp[8];
#pragma unroll
    for (int q = 0; q < 8; ++q) { al[q] = 0.f; asp[q] = 0.f; }
    const float4* lrow = (const float4*)(lw1 + tid * 512);
    const float4* srow = (const float4*)(sw1 + tid * 512);
    const float4* fs4 = (const float4*)fs;
    const float4* bs4 = (const float4*)bs;
    for (int d4 = 0; d4 < 64; ++d4) {
        float4 wlv = lrow[d4], wsv = srow[d4];
#pragma unroll
        for (int tt = 0; tt < 8; ++tt) {
            float4 e = fs4[tt * 64 + d4];
            al[tt]  += wlv.x * e.x + wlv.y * e.y + wlv.z * e.z + wlv.w * e.w;
            asp[tt] += wsv.x * e.x + wsv.y * e.y + wsv.z * e.z + wsv.w * e.w;
        }
    }
    for (int d4 = 0; d4 < 64; ++d4) {
        float4 wlv = lrow[64 + d4], wsv = srow[64 + d4];
#pragma unroll
        for (int tt = 0; tt < 8; ++tt) {
            float4 e = bs4[tt * 64 + d4];
            al[tt]  -= wlv.x * e.x + wlv.y * e.y + wlv.z * e.z + wlv.w * e.w;
            asp[tt] -= wsv.x * e.x + wsv.y * e.y + wsv.z * e.z + wsv.w * e.w;
        }
    }
    for (int tt = 0; tt < 8; ++tt) {
        int t = t0 + tt;
        if (t < NP1) { dlab[t * HDIM + tid] = al[tt]; dspl[t * HDIM + tid] = asp[tt]; }
    }
}

// ---------------- K6: pack lab_w2 into f16 MFMA B-fragments ----------------
// w2f[kb8][m][j] = (f16) lw2[m][kb8*8+j],  kb8=k>>3, j=k&7
__global__ void k_w2f(const float* __restrict__ lw2, _Float16* __restrict__ w2f) {
    int m = blockIdx.x, k = threadIdx.x;
    w2f[(((k >> 3) * LABV) + m) * 8 + (k & 7)] = (_Float16)lw2[m * HDIM + k];
}

// ---------------- K7: fused output kernel (MFMA f16) ----------------
// block = (jt, i); 256 threads (4 waves); out[i, jt*32 .. +31, 0..128]
// wave w owns m-tiles {2w, 2w+1}; both 16-row j-tiles; K=256 in 8 mfma steps.
__global__ __launch_bounds__(256) void k_out(const float* __restrict__ dlab, const float* __restrict__ dspl,
                                             const float* __restrict__ lb1, const float* __restrict__ sb1,
                                             const _Float16* __restrict__ w2f, const float* __restrict__ lb2,
                                             const float* __restrict__ sw2, const float* __restrict__ sb2,
                                             float* __restrict__ outp) {
    const int i = blockIdx.y, jtblk = blockIdx.x, tid = threadIdx.x;
    __shared__ float dli[HDIM], dsi[HDIM];
    __shared__ _Float16 hl[32 * 264];   // row stride 264 f16 (=33*16B) to spread banks

    dli[tid] = dlab[i * HDIM + tid] - lb1[tid];
    dsi[tid] = dspl[i * HDIM + tid] - sb1[tid];
    __syncthreads();

    // phase 1: hidden activations (f16) for the label MLP
    for (int j = 0; j < 32; ++j) {
        int jj = jtblk * 32 + j;
        float v = 0.f;
        if (jj < NP1) v = fmaxf(dlab[jj * HDIM + tid] - dli[tid], 0.f);
        hl[j * 264 + tid] = (_Float16)v;
    }

    // phase 1.5: split scores
    {
        int w = tid >> 6, l = tid & 63;
        float sw2v[4];
#pragma unroll
        for (int cc = 0; cc < 4; ++cc) sw2v[cc] = sw2[l + 64 * cc];
        float sb2v = sb2[0];
        for (int q = 0; q < 8; ++q) {
            int jj = jtblk * 32 + w * 8 + q;
            if (jj < NP1) {
                float sum = 0.f;
#pragma unroll
                for (int cc = 0; cc < 4; ++cc) {
                    int k = l + 64 * cc;
                    float v = fmaxf(dspl[jj * HDIM + k] - dsi[k], 0.f);
                    sum += v * sw2v[cc];
                }
#pragma unroll
                for (int off = 32; off > 0; off >>= 1) sum += __shfl_down(sum, off, 64);
                if (l == 0) outp[(size_t)(i * NP1 + jj) * OUTC + 128] = sum + sb2v;
            }
        }
    }
    __syncthreads();

    // phase 2: label GEMM via mfma_f32_16x16x32_f16
    const int w = tid >> 6, l = tid & 63;
    const int q = l >> 4, c16 = l & 15;
    f32x4 acc[2][2];
#pragma unroll
    for (int a = 0; a < 2; ++a)
#pragma unroll
        for (int b = 0; b < 2; ++b) acc[a][b] = (f32x4){0.f, 0.f, 0.f, 0.f};

    const int mt0 = w * 2;
#pragma unroll
    for (int kb = 0; kb < 8; ++kb) {
        // A-frags: lane holds hl[jt*16 + c16][kb*32 + q*8 .. +7]
        f16x8 a0 = *(const f16x8*)(hl + (0 * 16 + c16) * 264 + kb * 32 + q * 8);
        f16x8 a1 = *(const f16x8*)(hl + (1 * 16 + c16) * 264 + kb * 32 + q * 8);
        // B-frags: lane holds w2f[kb*4+q][mt*16 + c16][0..7]
        f16x8 b0 = *(const f16x8*)(w2f + (((kb * 4 + q) * LABV) + mt0 * 16 + c16) * 8);
        f16x8 b1 = *(const f16x8*)(w2f + (((kb * 4 + q) * LABV) + (mt0 + 1) * 16 + c16) * 8);
        acc[0][0] = __builtin_amdgcn_mfma_f32_16x16x32_f16(a0, b0, acc[0][0], 0, 0, 0);
        acc[0][1] = __builtin_amdgcn_mfma_f32_16x16x32_f16(a0, b1, acc[0][1], 0, 0, 0);
        acc[1][0] = __builtin_amdgcn_mfma_f32_16x16x32_f16(a1, b0, acc[1][0], 0, 0, 0);
        acc[1][1] = __builtin_amdgcn_mfma_f32_16x16x32_f16(a1, b1, acc[1][1], 0, 0, 0);
    }

    // epilogue: C/D layout col = lane&15, row = q*4 + reg
#pragma unroll
    for (int mb = 0; mb < 2; ++mb) {
        int m = (mt0 + mb) * 16 + c16;
        float bias = lb2[m];
#pragma unroll
        for (int jt = 0; jt < 2; ++jt) {
#pragma unroll
            for (int r = 0; r < 4; ++r) {
                int jj = jtblk * 32 + jt * 16 + q * 4 + r;
                if (jj < NP1) outp[(size_t)(i * NP1 + jj) * OUTC + m] = acc[jt][mb][r] + bias;
            }
        }
    }
}

// ---------------- launcher ----------------
extern "C" void kernel_launch(void* const* d_in, const int* in_sizes, int n_in,
                              void* d_out, int out_size, void* d_ws, size_t ws_size,
                              hipStream_t stream) {
    const int*   tag_ids  = (const int*)d_in[0];
    const int*   word_ids = (const int*)d_in[1];
    const float* tag_emb  = (const float*)d_in[2];
    const float* word_emb = (const float*)d_in[3];
    const float* wxf = (const float*)d_in[4];
    const float* whf = (const float*)d_in[5];
    const float* bf_ = (const float*)d_in[6];
    const float* wxb = (const float*)d_in[7];
    const float* whb = (const float*)d_in[8];
    const float* bb_ = (const float*)d_in[9];
    const float* lw1 = (const float*)d_in[10];
    const float* lb1 = (const float*)d_in[11];
    const float* lw2 = (const float*)d_in[12];
    const float* lb2 = (const float*)d_in[13];
    const float* sw1 = (const float*)d_in[14];
    const float* sb1 = (const float*)d_in[15];
    const float* sw2 = (const float*)d_in[16];
    const float* sb2 = (const float*)d_in[17];

    char* ws = (char*)d_ws;
    float*     emb  = (float*)(ws + OFF_EMB);
    float*     gx   = (float*)(ws + OFF_GX);
    uint4*     wreg = (uint4*)(ws + OFF_WREG);
    uint4*     wldsg= (uint4*)(ws + OFF_WLDS);
    float*     fm   = (float*)(ws + OFF_F);
    float*     bm   = (float*)(ws + OFF_B);
    float*     dlab = (float*)(ws + OFF_DL);
    float*     dspl = (float*)(ws + OFF_DS);
    _Float16*  w2f  = (_Float16*)(ws + OFF_W2F);
    float*     outp = (float*)d_out;

    k_embed<<<dim3(SEQ), dim3(EMBD), 0, stream>>>(tag_ids, word_ids, tag_emb, word_emb, emb);
    k_gx   <<<dim3(49, 2), dim3(256), 0, stream>>>(emb, wxf, bf_, wxb, bb_, gx);
    k_wconv<<<dim3(2, 128), dim3(256), 0, stream>>>(whf, whb, wreg, wldsg);
    k_w2f  <<<dim3(LABV), dim3(HDIM), 0, stream>>>(lw2, w2f);
    k_lstm <<<dim3(2), dim3(512), 0, stream>>>(wreg, wldsg, gx, fm, bm);
    k_dmat <<<dim3(49), dim3(256), 0, stream>>>(fm, bm, lw1, sw1, dlab, dspl);
    k_out  <<<dim3(13, NP1), dim3(256), 0, stream>>>(dlab, dspl, lb1, sb1, w2f, lb2, sw2, sb2, outp);
}